// Round 5
// baseline (3486.718 us; speedup 1.0000x reference)
//
#include <hip/hip_runtime.h>

typedef unsigned short ushort_t;

#define NTOK 262144   // B*L = 4*65536

__device__ __forceinline__ float bf2f(ushort_t u) {
    union { unsigned u; float f; } v; v.u = ((unsigned)u) << 16; return v.f;
}
__device__ __forceinline__ ushort_t f2bf(float f) {
    union { float f; unsigned u; } v; v.f = f;
    unsigned r = 0x7fffu + ((v.u >> 16) & 1u);
    return (ushort_t)((v.u + r) >> 16);
}
__device__ __forceinline__ float ldany(const void* p, long i, int isf32) {
    return isf32 ? ((const float*)p)[i] : bf2f(((const ushort_t*)p)[i]);
}

// ---- fp32 weight region layout in d_ws (float offsets), 1 MiB total ----
#define OFF_F0T 0
#define OFF_F1T 20480
#define OFF_G0T 40960
#define OFF_G1T 61440
#define OFF_RW  81920
#define OFF_SW  102400
#define OFF_FB  122880
#define OFF_GB  123520
#define OFF_RB  124160
#define OFF_SB  124800
#define OFF_WST 125440
#define OFF_BST 125472
#define OFF_W1  125504
#define OFF_B1  133696
#define OFF_W2T 133952
#define OFF_B2  199488
#define OFF_FLAG 199744    // dtype flag (1.0 = tensors are fp32)
#define W_TOTAL 262144
#define SKIP_OFF 262144    // fp32 skip accumulator in ws, 32 MiB
// (R3/R4 bit-identical errors across layouts prove ws_size >= 35 MiB.)

// r ping-pong chunks live in d_out (dead before k_final's output overwrite):
// byte offset (buf*32 + b*8) MiB, 8 MiB per (buf,b) chunk.
__device__ __forceinline__ float* rchunk(void* outb, int buf, int b) {
    return (float*)((char*)outb + (((long)buf * 32 + (long)b * 8) << 20));
}

__global__ void k_convert(const void* fw, const void* fb,
                          const void* gw, const void* gb,
                          const void* rw, const void* rb,
                          const void* sw, const void* sb,
                          const void* wst, const void* bst,
                          const void* w1, const void* b1,
                          const void* w2, const void* b2,
                          float* W) {
    __shared__ int sh;
    if (threadIdx.x == 0) sh = 0;
    __syncthreads();
    {   // dtype sniff: bf16 weights never carry exponent 0xFF; fp32 low halves
        // are ~uniform mantissa bits -> a hit within 4096 ushorts w.p. ~1-3e-4.
        const ushort_t* p = (const ushort_t*)fw;
        int f = 0;
        for (int j = 0; j < 16; j++) {
            ushort_t u = p[threadIdx.x * 16 + j];
            f |= (((u >> 7) & 0xFF) == 0xFF) ? 1 : 0;
        }
        if (f) atomicOr(&sh, 1);
    }
    __syncthreads();
    const int isf32 = sh;
    if (blockIdx.x == 0 && threadIdx.x == 0) W[OFF_FLAG] = (float)isf32;

    int tid = blockIdx.x * blockDim.x + threadIdx.x;
    int stride = gridDim.x * blockDim.x;
    for (int idx = tid; idx < 20480; idx += stride) {
        int wl = idx >> 10;
        int co = (idx >> 5) & 31;
        int ci = idx & 31;
        int tIdx = (wl * 32 + ci) * 32 + co;  // transposed [wl][ci][co]
        W[OFF_F0T + tIdx] = ldany(fw, (long)idx * 2 + 0, isf32);
        W[OFF_F1T + tIdx] = ldany(fw, (long)idx * 2 + 1, isf32);
        W[OFF_G0T + tIdx] = ldany(gw, (long)idx * 2 + 0, isf32);
        W[OFF_G1T + tIdx] = ldany(gw, (long)idx * 2 + 1, isf32);
        W[OFF_RW + idx] = ldany(rw, idx, isf32);
        W[OFF_SW + idx] = ldany(sw, idx, isf32);
    }
    for (int idx = tid; idx < 640; idx += stride) {
        W[OFF_FB + idx] = ldany(fb, idx, isf32);
        W[OFF_GB + idx] = ldany(gb, idx, isf32);
        W[OFF_RB + idx] = ldany(rb, idx, isf32);
        W[OFF_SB + idx] = ldany(sb, idx, isf32);
    }
    for (int idx = tid; idx < 32; idx += stride) {
        W[OFF_WST + idx] = ldany(wst, idx, isf32);
        W[OFF_BST + idx] = ldany(bst, idx, isf32);
    }
    for (int idx = tid; idx < 8192; idx += stride) W[OFF_W1 + idx] = ldany(w1, idx, isf32);
    for (int idx = tid; idx < 256; idx += stride) {
        W[OFF_B1 + idx] = ldany(b1, idx, isf32);
        W[OFF_B2 + idx] = ldany(b2, idx, isf32);
    }
    for (int idx = tid; idx < 65536; idx += stride) {
        int o = idx >> 8, ci = idx & 255;
        W[OFF_W2T + ci * 256 + o] = ldany(w2, idx, isf32);
    }
}

__global__ __launch_bounds__(256) void k_init(const void* __restrict__ x,
                                              const float* __restrict__ W,
                                              void* __restrict__ outb,
                                              float* __restrict__ skp) {
    int tid = blockIdx.x * blockDim.x + threadIdx.x;
    int b = tid >> 16, l = tid & 65535;
    const int isf32 = (W[OFF_FLAG] > 0.5f) ? 1 : 0;
    float xv = ldany(x, tid, isf32);
    float* ra = rchunk(outb, 0, b);
    #pragma unroll
    for (int c = 0; c < 32; c++) {
        ra[((long)c << 16) + l] = W[OFF_WST + c] * xv + W[OFF_BST + c];
        skp[((long)b << 21) + ((long)c << 16) + l] = 0.f;
    }
}

__global__ __launch_bounds__(256) void k_layer(const float* __restrict__ W,
                                               void* __restrict__ outb,
                                               float* __restrict__ skp,
                                               int bufin, int bufout,
                                               int wl, int off0, int off1) {
    int tid = blockIdx.x * blockDim.x + threadIdx.x;
    int b = tid >> 16, l = tid & 65535;
    const float* __restrict__ F0 = W + OFF_F0T + wl * 1024;
    const float* __restrict__ F1 = W + OFF_F1T + wl * 1024;
    const float* __restrict__ G0 = W + OFF_G0T + wl * 1024;
    const float* __restrict__ G1 = W + OFF_G1T + wl * 1024;
    const float* __restrict__ FB = W + OFF_FB + wl * 32;
    const float* __restrict__ GB = W + OFF_GB + wl * 32;
    const float* __restrict__ RWp = W + OFF_RW + wl * 1024;
    const float* __restrict__ SWp = W + OFF_SW + wl * 1024;
    const float* __restrict__ RB = W + OFF_RB + wl * 32;
    const float* __restrict__ SB = W + OFF_SB + wl * 32;

    const float* __restrict__ rin = rchunk(outb, bufin, b);
    float* __restrict__ rout = rchunk(outb, bufout, b);

    int l0 = l + off0, l1 = l + off1;
    bool v0 = ((unsigned)l0 < 65536u), v1 = ((unsigned)l1 < 65536u);
    int la = v0 ? l0 : 0;
    int lb = v1 ? l1 : 0;

    float f[32], g[32];
    #pragma unroll
    for (int co = 0; co < 32; co++) { f[co] = FB[co]; g[co] = GB[co]; }

    for (int ci = 0; ci < 32; ci++) {
        float a = rin[((long)ci << 16) + la];
        float h = rin[((long)ci << 16) + lb];
        a = v0 ? a : 0.f;
        h = v1 ? h : 0.f;
        const float* f0 = F0 + ci * 32;
        const float* f1 = F1 + ci * 32;
        const float* g0 = G0 + ci * 32;
        const float* g1 = G1 + ci * 32;
        #pragma unroll
        for (int co = 0; co < 32; co++) {
            f[co] += f0[co] * a + f1[co] * h;
            g[co] += g0[co] * a + g1[co] * h;
        }
    }
    float lo[32];
    #pragma unroll
    for (int co = 0; co < 32; co++) lo[co] = f[co] * g[co];

    float* __restrict__ skb = skp + ((long)b << 21) + l;
    for (int co = 0; co < 32; co++) {
        float s = SB[co], r = RB[co];
        const float* swr = SWp + co * 32;
        const float* rwr = RWp + co * 32;
        #pragma unroll
        for (int ci = 0; ci < 32; ci++) {
            s += swr[ci] * lo[ci];
            r += rwr[ci] * lo[ci];
        }
        skb[(long)co << 16] += s;
        rout[((long)co << 16) + l] = rin[((long)co << 16) + l] + r;
    }
}

__global__ __launch_bounds__(256) void k_final(const float* __restrict__ W,
                                               const float* __restrict__ skp,
                                               void* __restrict__ outv) {
    // h1 staged as bf16, channel-major: 32 KiB LDS, conflict-free both phases.
    __shared__ ushort_t h1s[256 * 64];
    int t = threadIdx.x & 63;
    int og = threadIdx.x >> 6;
    int tok = blockIdx.x * 64 + t;
    int b = tok >> 16, l = tok & 65535;
    const int isf32 = (W[OFF_FLAG] > 0.5f) ? 1 : 0;

    const float* __restrict__ skb = skp + ((long)b << 21) + l;
    float s[32];
    #pragma unroll
    for (int ci = 0; ci < 32; ci++) {
        float v = skb[(long)ci << 16];
        s[ci] = v > 0.f ? v : 0.f;
    }
    const float* __restrict__ w1 = W + OFF_W1 + (og * 64) * 32;
    const float* __restrict__ b1 = W + OFF_B1 + og * 64;
    #pragma unroll 4
    for (int o = 0; o < 64; o++) {
        float acc = b1[o];
        const float* wr = w1 + o * 32;
        #pragma unroll
        for (int ci = 0; ci < 32; ci++) acc += wr[ci] * s[ci];
        h1s[(og * 64 + o) * 64 + t] = f2bf(acc > 0.f ? acc : 0.f);
    }
    __syncthreads();
    float acc[64];
    const float* __restrict__ b2 = W + OFF_B2 + og * 64;
    #pragma unroll
    for (int o = 0; o < 64; o++) acc[o] = b2[o];
    const float* __restrict__ w2t = W + OFF_W2T + og * 64;
    for (int cc = 0; cc < 32; cc++) {
        float h[8];
        #pragma unroll
        for (int j = 0; j < 8; j++) h[j] = bf2f(h1s[(cc * 8 + j) * 64 + t]);
        #pragma unroll
        for (int j = 0; j < 8; j++) {
            const float* wr = w2t + (cc * 8 + j) * 256;
            float hv = h[j];
            #pragma unroll
            for (int o = 0; o < 64; o++) acc[o] += wr[o] * hv;
        }
    }
    long obase = ((long)b << 24) + ((long)(og * 64) << 16) + l;
    if (isf32) {
        float* ob = (float*)outv + obase;
        #pragma unroll
        for (int o = 0; o < 64; o++) ob[(long)o << 16] = acc[o];
    } else {
        ushort_t* ob = (ushort_t*)outv + obase;
        #pragma unroll
        for (int o = 0; o < 64; o++) ob[(long)o << 16] = f2bf(acc[o]);
    }
}

extern "C" void kernel_launch(void* const* d_in, const int* in_sizes, int n_in,
                              void* d_out, int out_size, void* d_ws, size_t ws_size,
                              hipStream_t stream) {
    const void* x    = d_in[0];
    const void* wst  = d_in[1];
    const void* bst  = d_in[2];
    const void* fw   = d_in[3];
    const void* fb   = d_in[4];
    const void* gw   = d_in[5];
    const void* gb   = d_in[6];
    const void* rw   = d_in[7];
    const void* rb   = d_in[8];
    const void* sw   = d_in[9];
    const void* sb   = d_in[10];
    const void* w1   = d_in[11];
    const void* b1   = d_in[12];
    const void* w2   = d_in[13];
    const void* b2   = d_in[14];

    float* W   = (float*)d_ws;
    float* skp = W + SKIP_OFF;   // fp32 skip accumulator in ws

    k_convert<<<64, 256, 0, stream>>>(fw, fb, gw, gb, rw, rb, sw, sb,
                                      wst, bst, w1, b1, w2, b2, W);
    k_init<<<NTOK / 256, 256, 0, stream>>>(x, W, d_out, skp);

    int cur = 0;
    for (int blk = 0; blk < 2; blk++) {
        int d = 1;
        for (int i = 0; i < 10; i++) {
            int off0, off1;
            if (i == 0) { off0 = -1; off1 = 0; }
            else        { off0 = -(d >> 1); off1 = (d >> 1); }
            k_layer<<<NTOK / 256, 256, 0, stream>>>(W, d_out, skp,
                                                    cur, cur ^ 1,
                                                    blk * 10 + i, off0, off1);
            cur ^= 1;
            d <<= 1;
        }
    }
    k_final<<<NTOK / 64, 256, 0, stream>>>(W, skp, d_out);
}